// Round 8
// baseline (503.555 us; speedup 1.0000x reference)
//
#include <hip/hip_runtime.h>
#include <hip/hip_bf16.h>
#include <hip/hip_cooperative_groups.h>

namespace cg = cooperative_groups;

typedef unsigned short ushort_t;
typedef __attribute__((ext_vector_type(8))) short short8;
typedef __attribute__((ext_vector_type(4))) float f32x4;

static __device__ inline ushort_t f2bfu(float f) {
    __hip_bfloat16 h = __float2bfloat16(f);
    ushort_t u; __builtin_memcpy(&u, &h, 2); return u;
}
static __device__ inline float bflo(unsigned int u) { return __uint_as_float(u << 16); }
static __device__ inline float bfhi(unsigned int u) { return __uint_as_float(u & 0xffff0000u); }

// ---------------------------------------------------------------------------
// Workspace (floats):
//   xA @0 (25600) | xB @25600 (25600) | wT @51200 (294912) | vwT @346112 (2048)
//   pooled @348160 (32) | fbf(bf16[400][64]) @348192 (12800) |
//   W1bf(bf16[96][128]) @360992 (6144) | ptbf(bf16[21][16]) @367136 (168)
// ---------------------------------------------------------------------------

// ---------------- prep: weight transposes (grid 80) ----------------
__global__ __launch_bounds__(256) void prep_kernel(
    const float* __restrict__ blk_w1, const float* __restrict__ blk_w2,
    const float* __restrict__ val_conv_w, const float* __restrict__ piece_table,
    const float* __restrict__ mlp_w1,
    float* __restrict__ wT, float* __restrict__ vwT,
    ushort_t* __restrict__ W1bfu, ushort_t* __restrict__ ptbfu,
    float* __restrict__ pooled)
{
    int b = blockIdx.x, tid = threadIdx.x;
    if (b < 72) {
        // transpose one 64(oc) x 64(r2) tile of layer l: src[oc][576] -> wT[r2][64]
        __shared__ float lds[64][65];
        int l = b / 9, t9 = b % 9;
        const float* src = ((l & 1) ? blk_w2 : blk_w1) + (l >> 1) * 36864;
        int r2l = tid & 63, ocq = tid >> 6;
        #pragma unroll
        for (int pp = 0; pp < 16; pp++) {
            int oc = pp * 4 + ocq;
            lds[oc][r2l] = src[oc * 576 + t9 * 64 + r2l];
        }
        __syncthreads();
        int ocl = tid & 63, r2q = tid >> 6;
        #pragma unroll
        for (int pp = 0; pp < 16; pp++) {
            int r2 = pp * 4 + r2q;
            wT[l * 36864 + (t9 * 64 + r2) * 64 + ocl] = lds[ocl][r2];
        }
    } else {
        int g = (b - 72) * 256 + tid;          // 0..2047
        for (int i = g; i < 12288; i += 2048)  // W1 bf16, rows 83..95 zero
            W1bfu[i] = (i < 83 * 128) ? f2bfu(mlp_w1[i]) : (ushort_t)0;
        if (g < 2048) vwT[g] = val_conv_w[(g & 31) * 64 + (g >> 5)];
        if (g < 336)  ptbfu[g] = f2bfu(piece_table[g]);
        if (g < 32)   pooled[g] = 0.f;
    }
}

// ---------------- fused encoder: stem + 8 convs, cooperative ----------------
__device__ __forceinline__ void conv_layer(
    float* lds, const float* __restrict__ in, float* __restrict__ out,
    const float* __restrict__ wTc, const float* __restrict__ bias,
    const float* __restrict__ scale, const float* __restrict__ offs,
    const float* __restrict__ resid, ushort_t* __restrict__ bf_out,
    const float* __restrict__ vwT, const float* __restrict__ vcb,
    float* __restrict__ pooled,
    int by, int x0, int w, int lane, int tid)
{
    for (int i4 = tid; i4 < 288; i4 += 256) {       // stage [3][6][64] halo
        int rr = i4 >> 4, cc4 = i4 & 15;
        int ry = rr / 6, rx = rr - ry * 6;
        int gy = by - 1 + ry, gx = x0 - 1 + rx;
        float4 v = make_float4(0.f, 0.f, 0.f, 0.f);
        if ((unsigned)gy < 20u && (unsigned)gx < 20u)
            v = *(const float4*)&in[(gy * 20 + gx) * 64 + cc4 * 4];
        *(float4*)&lds[rr * 64 + cc4 * 4] = v;
    }
    __syncthreads();

    int p = by * 20 + x0 + w;
    float acc0 = 0.f, acc1 = 0.f;
    #pragma unroll 3
    for (int t = 0; t < 9; t++) {
        int dy = t / 3, dx = t - dy * 3;
        const float* lrow = &lds[(dy * 6 + w + dx) * 64];
        const float* wrow = &wTc[t * 64 + lane];
        #pragma unroll
        for (int ic4 = 0; ic4 < 16; ic4++) {
            float4 a = *(const float4*)&lrow[ic4 * 4];
            float w0 = wrow[(ic4 * 4 + 0) * 576];
            float w1 = wrow[(ic4 * 4 + 1) * 576];
            float w2 = wrow[(ic4 * 4 + 2) * 576];
            float w3 = wrow[(ic4 * 4 + 3) * 576];
            acc0 += a.x * w0; acc1 += a.y * w1;
            acc0 += a.z * w2; acc1 += a.w * w3;
        }
    }

    float v0 = ((acc0 + acc1) + bias[lane]) * scale[lane] + offs[lane];
    if (resid) v0 += resid[p * 64 + lane];
    v0 = fmaxf(v0, 0.f);
    out[p * 64 + lane] = v0;

    if (bf_out) {
        bf_out[p * 64 + lane] = f2bfu(v0);
        // value head: 1x1 conv 64->32 + relu + pooled-sum over block's 4 positions
        __syncthreads();
        lds[w * 64 + lane] = v0;
        __syncthreads();
        if (tid < 128) {
            int ps = tid >> 5, oc = tid & 31;
            float a = 0.f;
            for (int ic = 0; ic < 64; ic++) a += lds[ps * 64 + ic] * vwT[ic * 32 + oc];
            lds[256 + tid] = fmaxf(a + vcb[oc], 0.f);
        }
        __syncthreads();
        if (tid < 32) {
            float s = lds[256 + tid] + lds[288 + tid] + lds[320 + tid] + lds[352 + tid];
            atomicAdd(&pooled[tid], s);
        }
    }
}

__global__ __launch_bounds__(256) void encoder_kernel(
    const float* __restrict__ board,
    const float* __restrict__ stem_w, const float* __restrict__ stem_b,
    const float* __restrict__ stem_s, const float* __restrict__ stem_o,
    float* __restrict__ xA, float* __restrict__ xB, const float* __restrict__ wT,
    const float* __restrict__ b1, const float* __restrict__ s1, const float* __restrict__ o1,
    const float* __restrict__ b2, const float* __restrict__ s2, const float* __restrict__ o2,
    ushort_t* __restrict__ fbf, const float* __restrict__ vwT,
    const float* __restrict__ vcb, float* __restrict__ pooled)
{
    cg::grid_group grid = cg::this_grid();
    __shared__ float lds[1536];
    int tid = threadIdx.x;
    int by = blockIdx.x / 5, x0 = (blockIdx.x % 5) * 4;
    int w = tid >> 6, lane = tid & 63;

    { // stem: 5->64 conv + bn + relu, wave = 1 position
        int y = by, x = x0 + w, p = by * 20 + x0 + w;
        float acc = 0.f;
        for (int ic = 0; ic < 5; ic++) {
            #pragma unroll
            for (int t = 0; t < 9; t++) {
                int yy = y + t / 3 - 1, xx = x + t % 3 - 1;
                if ((unsigned)yy < 20u && (unsigned)xx < 20u)
                    acc += board[ic * 400 + yy * 20 + xx] * stem_w[lane * 45 + ic * 9 + t];
            }
        }
        xA[p * 64 + lane] = fmaxf((acc + stem_b[lane]) * stem_s[lane] + stem_o[lane], 0.f);
    }
    grid.sync();

    for (int l = 0; l < 4; l++) {
        conv_layer(lds, xA, xB, wT + (2 * l) * 36864,
                   b1 + l * 64, s1 + l * 64, o1 + l * 64,
                   nullptr, nullptr, vwT, vcb, pooled, by, x0, w, lane, tid);
        grid.sync();
        bool last = (l == 3);
        conv_layer(lds, xB, xA, wT + (2 * l + 1) * 36864,
                   b2 + l * 64, s2 + l * 64, o2 + l * 64,
                   xA, last ? fbf : nullptr, vwT, vcb, pooled, by, x0, w, lane, tid);
        if (!last) grid.sync();
    }
}

// ---------------- policy head: MFMA GEMM, gather from L2 ----------------
__global__ __launch_bounds__(256, 4) void policy_kernel(
    const ushort_t* __restrict__ fbf,
    const int* __restrict__ piece_id, const float* __restrict__ anchor,
    const int* __restrict__ num_cells, const float* __restrict__ size_f,
    const int* __restrict__ cells,
    const ushort_t* __restrict__ W1bfu, const ushort_t* __restrict__ ptbfu,
    const float* __restrict__ b1, const float* __restrict__ w2,
    const float* __restrict__ b2p,
    float* __restrict__ out,
    const float* __restrict__ pooled, const float* __restrict__ self_rem,
    const float* __restrict__ opp_rem, const float* __restrict__ val_w1,
    const float* __restrict__ val_b1, const float* __restrict__ val_w2,
    const float* __restrict__ val_b2)
{
    __shared__ ushort_t Ft[4 * 1664];   // per-wave [16][104] bf16 F tiles

    // value head MLP (block 0, first wave)
    if (blockIdx.x == 0 && threadIdx.x < 64) {
        int j = threadIdx.x;
        float acc = val_b1[j];
        for (int k = 0; k < 74; k++) {
            float vk = (k < 32) ? pooled[k] * (1.0f / 400.0f)
                                : ((k < 53) ? self_rem[k - 32] : opp_rem[k - 53]);
            acc += vk * val_w1[k * 64 + j];
        }
        float h = fmaxf(acc, 0.f);
        float prod = h * val_w2[j];
        for (int off = 32; off > 0; off >>= 1) prod += __shfl_xor(prod, off);
        if (j == 0) out[400000] = tanhf(prod + val_b2[0]);
    }

    int l  = threadIdx.x & 63, w = threadIdx.x >> 6;
    int cl = l & 15, kq = l >> 4;       // MFMA col / k-quarter
    int mi = l >> 2, sl = l & 3;        // gather: move-in-tile / 16-ch slot
    ushort_t* Fl = Ft + w * 1664;

    // preload W1 B-fragments: bfr[ks][nt][e] = W1bf[ks*32+kq*8+e][nt*16+cl]
    short8 bfr[3][8];
    #pragma unroll
    for (int ks = 0; ks < 3; ks++) {
        #pragma unroll
        for (int nt = 0; nt < 8; nt++) {
            short8 s;
            #pragma unroll
            for (int e = 0; e < 8; e++)
                s[e] = (short)W1bfu[(ks * 32 + kq * 8 + e) * 128 + nt * 16 + cl];
            bfr[ks][nt] = s;
        }
    }
    float b1v[8], w2v[8];
    #pragma unroll
    for (int nt = 0; nt < 8; nt++) { b1v[nt] = b1[nt * 16 + cl]; w2v[nt] = w2[nt * 16 + cl]; }
    const float b2 = b2p[0];
    const uint4* fb4 = (const uint4*)fbf;   // [400][8] uint4 rows

    int gw = blockIdx.x * 4 + w;            // 0..4095
    for (int m0 = gw * 16; m0 < 400000; m0 += 4096 * 16) {
        int m = m0 + mi;
        int   pid = piece_id[m];
        int   nc  = num_cells[m];
        float2 an = ((const float2*)anchor)[m];
        float  sz = size_f[m];

        // gather-mean from L2-resident fmap: lane sums channels [sl*16, sl*16+16)
        float gacc[16];
        #pragma unroll
        for (int c = 0; c < 16; c++) gacc[c] = 0.f;
        for (int j = 0; j < nc; j++) {
            int2 cc = ((const int2*)cells)[m * 5 + j];
            int pc = cc.y * 20 + cc.x;
            uint4 qa = fb4[pc * 8 + sl * 2];
            uint4 qb = fb4[pc * 8 + sl * 2 + 1];
            gacc[0] += bflo(qa.x); gacc[1] += bfhi(qa.x);
            gacc[2] += bflo(qa.y); gacc[3] += bfhi(qa.y);
            gacc[4] += bflo(qa.z); gacc[5] += bfhi(qa.z);
            gacc[6] += bflo(qa.w); gacc[7] += bfhi(qa.w);
            gacc[8]  += bflo(qb.x); gacc[9]  += bfhi(qb.x);
            gacc[10] += bflo(qb.y); gacc[11] += bfhi(qb.y);
            gacc[12] += bflo(qb.z); gacc[13] += bfhi(qb.z);
            gacc[14] += bflo(qb.w); gacc[15] += bfhi(qb.w);
        }
        float scl = 1.0f / (float)nc;
        unsigned int pk[8];
        #pragma unroll
        for (int k = 0; k < 8; k++) {
            __hip_bfloat162 h2 = __float22bfloat162_rn(
                make_float2(gacc[2 * k] * scl, gacc[2 * k + 1] * scl));
            unsigned int u; __builtin_memcpy(&u, &h2, 4);
            pk[k] = u;
        }
        *(uint4*)(Fl + mi * 104 + sl * 16)     = make_uint4(pk[0], pk[1], pk[2], pk[3]);
        *(uint4*)(Fl + mi * 104 + sl * 16 + 8) = make_uint4(pk[4], pk[5], pk[6], pk[7]);
        if (sl == 0) { // piece embedding -> cols 64..79
            const uint4* pt = (const uint4*)ptbfu;
            *(uint4*)(Fl + mi * 104 + 64) = pt[pid * 2];
            *(uint4*)(Fl + mi * 104 + 72) = pt[pid * 2 + 1];
        }
        if (sl == 1) { // anchor, size, zero-pad -> cols 80..95
            unsigned int u0 = (unsigned int)f2bfu(an.x) | ((unsigned int)f2bfu(an.y) << 16);
            unsigned int u1 = (unsigned int)f2bfu(sz);
            *(uint4*)(Fl + mi * 104 + 80) = make_uint4(u0, u1, 0u, 0u);
            *(uint4*)(Fl + mi * 104 + 88) = make_uint4(0u, 0u, 0u, 0u);
        }
        // wave-local fence: cross-lane F writes must land before A-frag reads
        asm volatile("s_waitcnt lgkmcnt(0)" ::: "memory");

        short8 af0 = *(const short8*)(Fl + cl * 104 +      kq * 8);
        short8 af1 = *(const short8*)(Fl + cl * 104 + 32 + kq * 8);
        short8 af2 = *(const short8*)(Fl + cl * 104 + 64 + kq * 8);

        f32x4 acc[8];
        #pragma unroll
        for (int nt = 0; nt < 8; nt++) acc[nt] = (f32x4)0.f;
        #pragma unroll
        for (int nt = 0; nt < 8; nt++) {
            acc[nt] = __builtin_amdgcn_mfma_f32_16x16x32_bf16(af0, bfr[0][nt], acc[nt], 0, 0, 0);
            acc[nt] = __builtin_amdgcn_mfma_f32_16x16x32_bf16(af1, bfr[1][nt], acc[nt], 0, 0, 0);
            acc[nt] = __builtin_amdgcn_mfma_f32_16x16x32_bf16(af2, bfr[2][nt], acc[nt], 0, 0, 0);
        }

        // epilogue: relu(h)*w2, reduce over 16 col-lanes, write 16 logits
        float p0 = 0.f, p1 = 0.f, p2 = 0.f, p3 = 0.f;
        #pragma unroll
        for (int nt = 0; nt < 8; nt++) {
            p0 += fmaxf(acc[nt].x + b1v[nt], 0.f) * w2v[nt];
            p1 += fmaxf(acc[nt].y + b1v[nt], 0.f) * w2v[nt];
            p2 += fmaxf(acc[nt].z + b1v[nt], 0.f) * w2v[nt];
            p3 += fmaxf(acc[nt].w + b1v[nt], 0.f) * w2v[nt];
        }
        #pragma unroll
        for (int off = 1; off < 16; off <<= 1) {
            p0 += __shfl_xor(p0, off); p1 += __shfl_xor(p1, off);
            p2 += __shfl_xor(p2, off); p3 += __shfl_xor(p3, off);
        }
        if (cl < 4) {
            float v = p0;
            if (cl == 1) v = p1; else if (cl == 2) v = p2; else if (cl == 3) v = p3;
            out[m0 + kq * 4 + cl] = v + b2;
        }
    }
}

// ---------------------------------------------------------------------------
extern "C" void kernel_launch(void* const* d_in, const int* in_sizes, int n_in,
                              void* d_out, int out_size, void* d_ws, size_t ws_size,
                              hipStream_t stream) {
    const float* board      = (const float*)d_in[0];
    const float* self_rem   = (const float*)d_in[1];
    const float* opp_rem    = (const float*)d_in[2];
    const int*   piece_id   = (const int*)  d_in[3];
    const float* anchor     = (const float*)d_in[4];
    const int*   num_cells  = (const int*)  d_in[5];
    const float* size_f     = (const float*)d_in[6];
    const int*   cells      = (const int*)  d_in[7];
    const float* stem_w     = (const float*)d_in[8];
    const float* stem_b     = (const float*)d_in[9];
    const float* stem_s     = (const float*)d_in[10];
    const float* stem_o     = (const float*)d_in[11];
    const float* blk_w1     = (const float*)d_in[12];
    const float* blk_b1     = (const float*)d_in[13];
    const float* blk_s1     = (const float*)d_in[14];
    const float* blk_o1     = (const float*)d_in[15];
    const float* blk_w2     = (const float*)d_in[16];
    const float* blk_b2     = (const float*)d_in[17];
    const float* blk_s2     = (const float*)d_in[18];
    const float* blk_o2     = (const float*)d_in[19];
    const float* piece_tab  = (const float*)d_in[20];
    const float* mlp_w1     = (const float*)d_in[21];
    const float* mlp_b1     = (const float*)d_in[22];
    const float* mlp_w2     = (const float*)d_in[23];
    const float* mlp_b2     = (const float*)d_in[24];
    const float* val_conv_w = (const float*)d_in[25];
    const float* val_conv_b = (const float*)d_in[26];
    const float* val_w1     = (const float*)d_in[27];
    const float* val_b1     = (const float*)d_in[28];
    const float* val_w2     = (const float*)d_in[29];
    const float* val_b2     = (const float*)d_in[30];
    float* out = (float*)d_out;

    float* ws     = (float*)d_ws;
    float* xA     = ws;
    float* xB     = ws + 25600;
    float* wT     = ws + 51200;
    float* vwT    = ws + 346112;
    float* pooled = ws + 348160;
    ushort_t* fbf   = (ushort_t*)(ws + 348192);
    ushort_t* W1bfu = (ushort_t*)(ws + 360992);
    ushort_t* ptbfu = (ushort_t*)(ws + 367136);

    prep_kernel<<<80, 256, 0, stream>>>(
        blk_w1, blk_w2, val_conv_w, piece_tab, mlp_w1,
        wT, vwT, W1bfu, ptbfu, pooled);

    void* eargs[] = {
        (void*)&board, (void*)&stem_w, (void*)&stem_b, (void*)&stem_s, (void*)&stem_o,
        (void*)&xA, (void*)&xB, (void*)&wT,
        (void*)&blk_b1, (void*)&blk_s1, (void*)&blk_o1,
        (void*)&blk_b2, (void*)&blk_s2, (void*)&blk_o2,
        (void*)&fbf, (void*)&vwT, (void*)&val_conv_b, (void*)&pooled
    };
    (void)hipLaunchCooperativeKernel((const void*)encoder_kernel,
                                     dim3(100), dim3(256), eargs, 0, stream);

    policy_kernel<<<1024, 256, 0, stream>>>(
        fbf, piece_id, anchor, num_cells, size_f, cells,
        W1bfu, ptbfu, mlp_b1, mlp_w2, mlp_b2, out,
        pooled, self_rem, opp_rem, val_w1, val_b1, val_w2, val_b2);
}

// Round 9
// 265.401 us; speedup vs baseline: 1.8973x; 1.8973x over previous
//
#include <hip/hip_runtime.h>
#include <hip/hip_bf16.h>

typedef unsigned short ushort_t;
typedef __attribute__((ext_vector_type(8))) short short8;
typedef __attribute__((ext_vector_type(4))) float f32x4;

static __device__ inline ushort_t f2bfu(float f) {
    __hip_bfloat16 h = __float2bfloat16(f);
    ushort_t u; __builtin_memcpy(&u, &h, 2); return u;
}
static __device__ inline float bflo(unsigned int u) { return __uint_as_float(u << 16); }
static __device__ inline float bfhi(unsigned int u) { return __uint_as_float(u & 0xffff0000u); }

// ---------------------------------------------------------------------------
// Workspace (floats):
//   xA @0 (25600) | xB @25600 (25600) | wT @51200 (294912) | vwT @346112 (2048)
//   pooled @348160 (32) | fbf(bf16[400][64]) @348192 (12800) |
//   W1bf(bf16[96][128]) @360992 (6144) | ptbf(bf16[21][16]) @367136 (168)
// ---------------------------------------------------------------------------

// ---------------- prep: weight transposes + misc + stem (grid 180) --------
__global__ __launch_bounds__(256) void prep_kernel(
    const float* __restrict__ board,
    const float* __restrict__ stem_w, const float* __restrict__ stem_b,
    const float* __restrict__ stem_s, const float* __restrict__ stem_o,
    float* __restrict__ xA,
    const float* __restrict__ blk_w1, const float* __restrict__ blk_w2,
    const float* __restrict__ val_conv_w, const float* __restrict__ piece_table,
    const float* __restrict__ mlp_w1,
    float* __restrict__ wT, float* __restrict__ vwT,
    ushort_t* __restrict__ W1bfu, ushort_t* __restrict__ ptbfu,
    float* __restrict__ pooled)
{
    int b = blockIdx.x, tid = threadIdx.x;
    if (b < 72) {
        // transpose one 64(oc) x 64(r2) tile of layer l: src[oc][576] -> wT[r2][64]
        __shared__ float lds[64][65];
        int l = b / 9, t9 = b % 9;
        const float* src = ((l & 1) ? blk_w2 : blk_w1) + (l >> 1) * 36864;
        int r2l = tid & 63, ocq = tid >> 6;
        #pragma unroll
        for (int pp = 0; pp < 16; pp++) {
            int oc = pp * 4 + ocq;
            lds[oc][r2l] = src[oc * 576 + t9 * 64 + r2l];
        }
        __syncthreads();
        int ocl = tid & 63, r2q = tid >> 6;
        #pragma unroll
        for (int pp = 0; pp < 16; pp++) {
            int r2 = pp * 4 + r2q;
            wT[l * 36864 + (t9 * 64 + r2) * 64 + ocl] = lds[ocl][r2];
        }
    } else if (b < 80) {
        int g = (b - 72) * 256 + tid;          // 0..2047
        for (int i = g; i < 12288; i += 2048)  // W1 bf16, rows 83..95 zero
            W1bfu[i] = (i < 83 * 128) ? f2bfu(mlp_w1[i]) : (ushort_t)0;
        if (g < 2048) vwT[g] = val_conv_w[(g & 31) * 64 + (g >> 5)];
        if (g < 336)  ptbfu[g] = f2bfu(piece_table[g]);
        if (g < 32)   pooled[g] = 0.f;
    } else {
        // stem: 5->64 conv + bn + relu, wave = 1 position
        int wv   = (b - 80) * 4 + (tid >> 6);  // 0..399
        int lane = tid & 63;
        int y = wv / 20, x = wv % 20;
        float acc = 0.f;
        for (int ic = 0; ic < 5; ic++) {
            #pragma unroll
            for (int t = 0; t < 9; t++) {
                int yy = y + t / 3 - 1, xx = x + t % 3 - 1;
                if ((unsigned)yy < 20u && (unsigned)xx < 20u)
                    acc += board[ic * 400 + yy * 20 + xx] * stem_w[lane * 45 + ic * 9 + t];
            }
        }
        xA[wv * 64 + lane] = fmaxf((acc + stem_b[lane]) * stem_s[lane] + stem_o[lane], 0.f);
    }
}

// ---------------- conv 3x3: 400 blocks x 512, 8-way ic-split ----------------
__global__ __launch_bounds__(512) void conv_ksplit(
    const float* __restrict__ in, float* __restrict__ out,
    const float* __restrict__ wTc, const float* __restrict__ bias,
    const float* __restrict__ scale, const float* __restrict__ offs,
    const float* __restrict__ resid,
    ushort_t* __restrict__ bf_out,             // non-null on final conv
    const float* __restrict__ vwT, const float* __restrict__ vcb,
    float* __restrict__ pooled)
{
    __shared__ float acts[576];                // [9 cells][64 ch]
    __shared__ float red[8][64];
    int tid = threadIdx.x;
    int p = blockIdx.x, y = p / 20, x = p % 20;
    int lane = tid & 63, w = tid >> 6;         // w = ic-slice 0..7

    for (int i = tid; i < 144; i += 512) {     // stage 3x3 halo, zero-padded
        int c = i >> 4, q = i & 15;
        int dy = c / 3, dx = c % 3;
        int gy = y + dy - 1, gx = x + dx - 1;
        float4 v = make_float4(0.f, 0.f, 0.f, 0.f);
        if ((unsigned)gy < 20u && (unsigned)gx < 20u)
            v = *(const float4*)&in[(gy * 20 + gx) * 64 + q * 4];
        *(float4*)&acts[c * 64 + q * 4] = v;
    }
    __syncthreads();

    float a0 = 0.f, a1 = 0.f;
    #pragma unroll
    for (int t = 0; t < 9; t++) {
        float4 av0 = *(const float4*)&acts[t * 64 + w * 8];
        float4 av1 = *(const float4*)&acts[t * 64 + w * 8 + 4];
        const float* wp = &wTc[(w * 8 * 9 + t) * 64 + lane];   // + j*576 per ic
        float w0 = wp[0 * 576], w1 = wp[1 * 576], w2 = wp[2 * 576], w3 = wp[3 * 576];
        float w4 = wp[4 * 576], w5 = wp[5 * 576], w6 = wp[6 * 576], w7 = wp[7 * 576];
        a0 += av0.x * w0 + av0.y * w1; a1 += av0.z * w2 + av0.w * w3;
        a0 += av1.x * w4 + av1.y * w5; a1 += av1.z * w6 + av1.w * w7;
    }
    red[w][lane] = a0 + a1;
    __syncthreads();

    if (tid < 64) {
        float tot = 0.f;
        #pragma unroll
        for (int k = 0; k < 8; k++) tot += red[k][tid];
        float v0 = (tot + bias[tid]) * scale[tid] + offs[tid];
        if (resid) v0 += resid[p * 64 + tid];
        v0 = fmaxf(v0, 0.f);
        out[p * 64 + tid] = v0;
        if (bf_out) { bf_out[p * 64 + tid] = f2bfu(v0); acts[tid] = v0; }
    }
    if (bf_out) {
        // value head: 1x1 conv 64->32 + relu + atomic pooled-sum (1 position)
        __syncthreads();
        if (tid < 32) {
            float a = 0.f;
            for (int ic = 0; ic < 64; ic++) a += acts[ic] * vwT[ic * 32 + tid];
            atomicAdd(&pooled[tid], fmaxf(a + vcb[tid], 0.f));
        }
    }
}

// ---------------- policy head: MFMA GEMM, gather from L2 (R8-identical) ----
__global__ __launch_bounds__(256, 4) void policy_kernel(
    const ushort_t* __restrict__ fbf,
    const int* __restrict__ piece_id, const float* __restrict__ anchor,
    const int* __restrict__ num_cells, const float* __restrict__ size_f,
    const int* __restrict__ cells,
    const ushort_t* __restrict__ W1bfu, const ushort_t* __restrict__ ptbfu,
    const float* __restrict__ b1, const float* __restrict__ w2,
    const float* __restrict__ b2p,
    float* __restrict__ out,
    const float* __restrict__ pooled, const float* __restrict__ self_rem,
    const float* __restrict__ opp_rem, const float* __restrict__ val_w1,
    const float* __restrict__ val_b1, const float* __restrict__ val_w2,
    const float* __restrict__ val_b2)
{
    __shared__ ushort_t Ft[4 * 1664];   // per-wave [16][104] bf16 F tiles

    // value head MLP (block 0, first wave)
    if (blockIdx.x == 0 && threadIdx.x < 64) {
        int j = threadIdx.x;
        float acc = val_b1[j];
        for (int k = 0; k < 74; k++) {
            float vk = (k < 32) ? pooled[k] * (1.0f / 400.0f)
                                : ((k < 53) ? self_rem[k - 32] : opp_rem[k - 53]);
            acc += vk * val_w1[k * 64 + j];
        }
        float h = fmaxf(acc, 0.f);
        float prod = h * val_w2[j];
        for (int off = 32; off > 0; off >>= 1) prod += __shfl_xor(prod, off);
        if (j == 0) out[400000] = tanhf(prod + val_b2[0]);
    }

    int l  = threadIdx.x & 63, w = threadIdx.x >> 6;
    int cl = l & 15, kq = l >> 4;       // MFMA col / k-quarter
    int mi = l >> 2, sl = l & 3;        // gather: move-in-tile / 16-ch slot
    ushort_t* Fl = Ft + w * 1664;

    // preload W1 B-fragments: bfr[ks][nt][e] = W1bf[ks*32+kq*8+e][nt*16+cl]
    short8 bfr[3][8];
    #pragma unroll
    for (int ks = 0; ks < 3; ks++) {
        #pragma unroll
        for (int nt = 0; nt < 8; nt++) {
            short8 s;
            #pragma unroll
            for (int e = 0; e < 8; e++)
                s[e] = (short)W1bfu[(ks * 32 + kq * 8 + e) * 128 + nt * 16 + cl];
            bfr[ks][nt] = s;
        }
    }
    float b1v[8], w2v[8];
    #pragma unroll
    for (int nt = 0; nt < 8; nt++) { b1v[nt] = b1[nt * 16 + cl]; w2v[nt] = w2[nt * 16 + cl]; }
    const float b2 = b2p[0];
    const uint4* fb4 = (const uint4*)fbf;   // [400][8] uint4 rows

    int gw = blockIdx.x * 4 + w;            // 0..4095
    for (int m0 = gw * 16; m0 < 400000; m0 += 4096 * 16) {
        int m = m0 + mi;
        int   pid = piece_id[m];
        int   nc  = num_cells[m];
        float2 an = ((const float2*)anchor)[m];
        float  sz = size_f[m];

        // gather-mean from L2-resident fmap: lane sums channels [sl*16, sl*16+16)
        float gacc[16];
        #pragma unroll
        for (int c = 0; c < 16; c++) gacc[c] = 0.f;
        for (int j = 0; j < nc; j++) {
            int2 cc = ((const int2*)cells)[m * 5 + j];
            int pc = cc.y * 20 + cc.x;
            uint4 qa = fb4[pc * 8 + sl * 2];
            uint4 qb = fb4[pc * 8 + sl * 2 + 1];
            gacc[0] += bflo(qa.x); gacc[1] += bfhi(qa.x);
            gacc[2] += bflo(qa.y); gacc[3] += bfhi(qa.y);
            gacc[4] += bflo(qa.z); gacc[5] += bfhi(qa.z);
            gacc[6] += bflo(qa.w); gacc[7] += bfhi(qa.w);
            gacc[8]  += bflo(qb.x); gacc[9]  += bfhi(qb.x);
            gacc[10] += bflo(qb.y); gacc[11] += bfhi(qb.y);
            gacc[12] += bflo(qb.z); gacc[13] += bfhi(qb.z);
            gacc[14] += bflo(qb.w); gacc[15] += bfhi(qb.w);
        }
        float scl = 1.0f / (float)nc;
        unsigned int pk[8];
        #pragma unroll
        for (int k = 0; k < 8; k++) {
            __hip_bfloat162 h2 = __float22bfloat162_rn(
                make_float2(gacc[2 * k] * scl, gacc[2 * k + 1] * scl));
            unsigned int u; __builtin_memcpy(&u, &h2, 4);
            pk[k] = u;
        }
        *(uint4*)(Fl + mi * 104 + sl * 16)     = make_uint4(pk[0], pk[1], pk[2], pk[3]);
        *(uint4*)(Fl + mi * 104 + sl * 16 + 8) = make_uint4(pk[4], pk[5], pk[6], pk[7]);
        if (sl == 0) { // piece embedding -> cols 64..79
            const uint4* pt = (const uint4*)ptbfu;
            *(uint4*)(Fl + mi * 104 + 64) = pt[pid * 2];
            *(uint4*)(Fl + mi * 104 + 72) = pt[pid * 2 + 1];
        }
        if (sl == 1) { // anchor, size, zero-pad -> cols 80..95
            unsigned int u0 = (unsigned int)f2bfu(an.x) | ((unsigned int)f2bfu(an.y) << 16);
            unsigned int u1 = (unsigned int)f2bfu(sz);
            *(uint4*)(Fl + mi * 104 + 80) = make_uint4(u0, u1, 0u, 0u);
            *(uint4*)(Fl + mi * 104 + 88) = make_uint4(0u, 0u, 0u, 0u);
        }
        // wave-local fence: cross-lane F writes must land before A-frag reads
        asm volatile("s_waitcnt lgkmcnt(0)" ::: "memory");

        short8 af0 = *(const short8*)(Fl + cl * 104 +      kq * 8);
        short8 af1 = *(const short8*)(Fl + cl * 104 + 32 + kq * 8);
        short8 af2 = *(const short8*)(Fl + cl * 104 + 64 + kq * 8);

        f32x4 acc[8];
        #pragma unroll
        for (int nt = 0; nt < 8; nt++) acc[nt] = (f32x4)0.f;
        #pragma unroll
        for (int nt = 0; nt < 8; nt++) {
            acc[nt] = __builtin_amdgcn_mfma_f32_16x16x32_bf16(af0, bfr[0][nt], acc[nt], 0, 0, 0);
            acc[nt] = __builtin_amdgcn_mfma_f32_16x16x32_bf16(af1, bfr[1][nt], acc[nt], 0, 0, 0);
            acc[nt] = __builtin_amdgcn_mfma_f32_16x16x32_bf16(af2, bfr[2][nt], acc[nt], 0, 0, 0);
        }

        // epilogue: relu(h)*w2, reduce over 16 col-lanes, write 16 logits
        float p0 = 0.f, p1 = 0.f, p2 = 0.f, p3 = 0.f;
        #pragma unroll
        for (int nt = 0; nt < 8; nt++) {
            p0 += fmaxf(acc[nt].x + b1v[nt], 0.f) * w2v[nt];
            p1 += fmaxf(acc[nt].y + b1v[nt], 0.f) * w2v[nt];
            p2 += fmaxf(acc[nt].z + b1v[nt], 0.f) * w2v[nt];
            p3 += fmaxf(acc[nt].w + b1v[nt], 0.f) * w2v[nt];
        }
        #pragma unroll
        for (int off = 1; off < 16; off <<= 1) {
            p0 += __shfl_xor(p0, off); p1 += __shfl_xor(p1, off);
            p2 += __shfl_xor(p2, off); p3 += __shfl_xor(p3, off);
        }
        if (cl < 4) {
            float v = p0;
            if (cl == 1) v = p1; else if (cl == 2) v = p2; else if (cl == 3) v = p3;
            out[m0 + kq * 4 + cl] = v + b2;
        }
    }
}

// ---------------------------------------------------------------------------
extern "C" void kernel_launch(void* const* d_in, const int* in_sizes, int n_in,
                              void* d_out, int out_size, void* d_ws, size_t ws_size,
                              hipStream_t stream) {
    const float* board      = (const float*)d_in[0];
    const float* self_rem   = (const float*)d_in[1];
    const float* opp_rem    = (const float*)d_in[2];
    const int*   piece_id   = (const int*)  d_in[3];
    const float* anchor     = (const float*)d_in[4];
    const int*   num_cells  = (const int*)  d_in[5];
    const float* size_f     = (const float*)d_in[6];
    const int*   cells      = (const int*)  d_in[7];
    const float* stem_w     = (const float*)d_in[8];
    const float* stem_b     = (const float*)d_in[9];
    const float* stem_s     = (const float*)d_in[10];
    const float* stem_o     = (const float*)d_in[11];
    const float* blk_w1     = (const float*)d_in[12];
    const float* blk_b1     = (const float*)d_in[13];
    const float* blk_s1     = (const float*)d_in[14];
    const float* blk_o1     = (const float*)d_in[15];
    const float* blk_w2     = (const float*)d_in[16];
    const float* blk_b2     = (const float*)d_in[17];
    const float* blk_s2     = (const float*)d_in[18];
    const float* blk_o2     = (const float*)d_in[19];
    const float* piece_tab  = (const float*)d_in[20];
    const float* mlp_w1     = (const float*)d_in[21];
    const float* mlp_b1     = (const float*)d_in[22];
    const float* mlp_w2     = (const float*)d_in[23];
    const float* mlp_b2     = (const float*)d_in[24];
    const float* val_conv_w = (const float*)d_in[25];
    const float* val_conv_b = (const float*)d_in[26];
    const float* val_w1     = (const float*)d_in[27];
    const float* val_b1     = (const float*)d_in[28];
    const float* val_w2     = (const float*)d_in[29];
    const float* val_b2     = (const float*)d_in[30];
    float* out = (float*)d_out;

    float* ws     = (float*)d_ws;
    float* xA     = ws;
    float* xB     = ws + 25600;
    float* wT     = ws + 51200;
    float* vwT    = ws + 346112;
    float* pooled = ws + 348160;
    ushort_t* fbf   = (ushort_t*)(ws + 348192);
    ushort_t* W1bfu = (ushort_t*)(ws + 360992);
    ushort_t* ptbfu = (ushort_t*)(ws + 367136);

    prep_kernel<<<180, 256, 0, stream>>>(
        board, stem_w, stem_b, stem_s, stem_o, xA,
        blk_w1, blk_w2, val_conv_w, piece_tab, mlp_w1,
        wT, vwT, W1bfu, ptbfu, pooled);

    for (int l = 0; l < 4; l++) {
        bool last = (l == 3);
        conv_ksplit<<<400, 512, 0, stream>>>(
            xA, xB, wT + (2 * l) * 36864,
            blk_b1 + l * 64, blk_s1 + l * 64, blk_o1 + l * 64,
            nullptr, nullptr, vwT, val_conv_b, pooled);
        conv_ksplit<<<400, 512, 0, stream>>>(
            xB, xA, wT + (2 * l + 1) * 36864,
            blk_b2 + l * 64, blk_s2 + l * 64, blk_o2 + l * 64,
            xA, last ? fbf : nullptr, vwT, val_conv_b, pooled);
    }

    policy_kernel<<<1024, 256, 0, stream>>>(
        fbf, piece_id, anchor, num_cells, size_f, cells,
        W1bfu, ptbfu, mlp_b1, mlp_w2, mlp_b2, out,
        pooled, self_rem, opp_rem, val_w1, val_b1, val_w2, val_b2);
}

// Round 10
// 237.088 us; speedup vs baseline: 2.1239x; 1.1194x over previous
//
#include <hip/hip_runtime.h>
#include <hip/hip_bf16.h>

typedef unsigned short ushort_t;
typedef __attribute__((ext_vector_type(8))) short short8;
typedef __attribute__((ext_vector_type(4))) float f32x4;

static __device__ inline ushort_t f2bfu(float f) {
    __hip_bfloat16 h = __float2bfloat16(f);
    ushort_t u; __builtin_memcpy(&u, &h, 2); return u;
}
static __device__ inline float bflo(unsigned int u) { return __uint_as_float(u << 16); }
static __device__ inline float bfhi(unsigned int u) { return __uint_as_float(u & 0xffff0000u); }

// ---------------------------------------------------------------------------
// Workspace (floats):
//   xA @0 (25600) | xB @25600 (25600) | wT @51200 (294912) | vwT @346112 (2048)
//   pooled @348160 (32) | fbf(bf16[400][64]) @348192 (12800) |
//   W1bf(bf16[96][128]) @360992 (6144) | ptbf(bf16[21][16]) @367136 (168)
// ---------------------------------------------------------------------------

// ---------------- prep: weight transposes + misc + stem (grid 180) --------
__global__ __launch_bounds__(256) void prep_kernel(
    const float* __restrict__ board,
    const float* __restrict__ stem_w, const float* __restrict__ stem_b,
    const float* __restrict__ stem_s, const float* __restrict__ stem_o,
    float* __restrict__ xA,
    const float* __restrict__ blk_w1, const float* __restrict__ blk_w2,
    const float* __restrict__ val_conv_w, const float* __restrict__ piece_table,
    const float* __restrict__ mlp_w1,
    float* __restrict__ wT, float* __restrict__ vwT,
    ushort_t* __restrict__ W1bfu, ushort_t* __restrict__ ptbfu,
    float* __restrict__ pooled)
{
    int b = blockIdx.x, tid = threadIdx.x;
    if (b < 72) {
        // transpose one 64(oc) x 64(r2) tile of layer l: src[oc][576] -> wT[r2][64]
        __shared__ float lds[64][65];
        int l = b / 9, t9 = b % 9;
        const float* src = ((l & 1) ? blk_w2 : blk_w1) + (l >> 1) * 36864;
        int r2l = tid & 63, ocq = tid >> 6;
        #pragma unroll
        for (int pp = 0; pp < 16; pp++) {
            int oc = pp * 4 + ocq;
            lds[oc][r2l] = src[oc * 576 + t9 * 64 + r2l];
        }
        __syncthreads();
        int ocl = tid & 63, r2q = tid >> 6;
        #pragma unroll
        for (int pp = 0; pp < 16; pp++) {
            int r2 = pp * 4 + r2q;
            wT[l * 36864 + (t9 * 64 + r2) * 64 + ocl] = lds[ocl][r2];
        }
    } else if (b < 80) {
        int g = (b - 72) * 256 + tid;          // 0..2047
        for (int i = g; i < 12288; i += 2048)  // W1 bf16, rows 83..95 zero
            W1bfu[i] = (i < 83 * 128) ? f2bfu(mlp_w1[i]) : (ushort_t)0;
        if (g < 2048) vwT[g] = val_conv_w[(g & 31) * 64 + (g >> 5)];
        if (g < 336)  ptbfu[g] = f2bfu(piece_table[g]);
        if (g < 32)   pooled[g] = 0.f;
    } else {
        // stem: 5->64 conv + bn + relu, wave = 1 position
        int wv   = (b - 80) * 4 + (tid >> 6);  // 0..399
        int lane = tid & 63;
        int y = wv / 20, x = wv % 20;
        float acc = 0.f;
        for (int ic = 0; ic < 5; ic++) {
            #pragma unroll
            for (int t = 0; t < 9; t++) {
                int yy = y + t / 3 - 1, xx = x + t % 3 - 1;
                if ((unsigned)yy < 20u && (unsigned)xx < 20u)
                    acc += board[ic * 400 + yy * 20 + xx] * stem_w[lane * 45 + ic * 9 + t];
            }
        }
        xA[wv * 64 + lane] = fmaxf((acc + stem_b[lane]) * stem_s[lane] + stem_o[lane], 0.f);
    }
}

// ---------------- conv 3x3: 400 blocks x 512, 8-way ic-split ----------------
__global__ __launch_bounds__(512) void conv_ksplit(
    const float* __restrict__ in, float* __restrict__ out,
    const float* __restrict__ wTc, const float* __restrict__ bias,
    const float* __restrict__ scale, const float* __restrict__ offs,
    const float* __restrict__ resid,
    ushort_t* __restrict__ bf_out,             // non-null on final conv
    const float* __restrict__ vwT, const float* __restrict__ vcb,
    float* __restrict__ pooled)
{
    __shared__ float acts[576];                // [9 cells][64 ch]
    __shared__ float red[8][64];
    int tid = threadIdx.x;
    int p = blockIdx.x, y = p / 20, x = p % 20;
    int lane = tid & 63, w = tid >> 6;         // w = ic-slice 0..7

    for (int i = tid; i < 144; i += 512) {     // stage 3x3 halo, zero-padded
        int c = i >> 4, q = i & 15;
        int dy = c / 3, dx = c % 3;
        int gy = y + dy - 1, gx = x + dx - 1;
        float4 v = make_float4(0.f, 0.f, 0.f, 0.f);
        if ((unsigned)gy < 20u && (unsigned)gx < 20u)
            v = *(const float4*)&in[(gy * 20 + gx) * 64 + q * 4];
        *(float4*)&acts[c * 64 + q * 4] = v;
    }
    __syncthreads();

    float a0 = 0.f, a1 = 0.f;
    #pragma unroll
    for (int t = 0; t < 9; t++) {
        float4 av0 = *(const float4*)&acts[t * 64 + w * 8];
        float4 av1 = *(const float4*)&acts[t * 64 + w * 8 + 4];
        const float* wp = &wTc[(w * 8 * 9 + t) * 64 + lane];   // + j*576 per ic
        float w0 = wp[0 * 576], w1 = wp[1 * 576], w2 = wp[2 * 576], w3 = wp[3 * 576];
        float w4 = wp[4 * 576], w5 = wp[5 * 576], w6 = wp[6 * 576], w7 = wp[7 * 576];
        a0 += av0.x * w0 + av0.y * w1; a1 += av0.z * w2 + av0.w * w3;
        a0 += av1.x * w4 + av1.y * w5; a1 += av1.z * w6 + av1.w * w7;
    }
    red[w][lane] = a0 + a1;
    __syncthreads();

    if (tid < 64) {
        float tot = 0.f;
        #pragma unroll
        for (int k = 0; k < 8; k++) tot += red[k][tid];
        float v0 = (tot + bias[tid]) * scale[tid] + offs[tid];
        if (resid) v0 += resid[p * 64 + tid];
        v0 = fmaxf(v0, 0.f);
        out[p * 64 + tid] = v0;
        if (bf_out) { bf_out[p * 64 + tid] = f2bfu(v0); acts[tid] = v0; }
    }
    if (bf_out) {
        // value head: 1x1 conv 64->32 + relu + atomic pooled-sum (1 position)
        __syncthreads();
        if (tid < 32) {
            float a = 0.f;
            for (int ic = 0; ic < 64; ic++) a += acts[ic] * vwT[ic * 32 + tid];
            atomicAdd(&pooled[tid], fmaxf(a + vcb[tid], 0.f));
        }
    }
}

// ---------------- policy head: MFMA GEMM, gather from L2 ----------------
// launch_bounds (256,2): R9's (256,4) forced VGPR=64 -> bfr[3][8] spilled to
// scratch (WRITE_SIZE 49.7MB, FETCH 158MB). (256,2) is the R7-proven budget.
__global__ __launch_bounds__(256, 2) void policy_kernel(
    const ushort_t* __restrict__ fbf,
    const int* __restrict__ piece_id, const float* __restrict__ anchor,
    const int* __restrict__ num_cells, const float* __restrict__ size_f,
    const int* __restrict__ cells,
    const ushort_t* __restrict__ W1bfu, const ushort_t* __restrict__ ptbfu,
    const float* __restrict__ b1, const float* __restrict__ w2,
    const float* __restrict__ b2p,
    float* __restrict__ out,
    const float* __restrict__ pooled, const float* __restrict__ self_rem,
    const float* __restrict__ opp_rem, const float* __restrict__ val_w1,
    const float* __restrict__ val_b1, const float* __restrict__ val_w2,
    const float* __restrict__ val_b2)
{
    __shared__ ushort_t Ft[4 * 1664];   // per-wave [16][104] bf16 F tiles

    // value head MLP (block 0, first wave)
    if (blockIdx.x == 0 && threadIdx.x < 64) {
        int j = threadIdx.x;
        float acc = val_b1[j];
        for (int k = 0; k < 74; k++) {
            float vk = (k < 32) ? pooled[k] * (1.0f / 400.0f)
                                : ((k < 53) ? self_rem[k - 32] : opp_rem[k - 53]);
            acc += vk * val_w1[k * 64 + j];
        }
        float h = fmaxf(acc, 0.f);
        float prod = h * val_w2[j];
        for (int off = 32; off > 0; off >>= 1) prod += __shfl_xor(prod, off);
        if (j == 0) out[400000] = tanhf(prod + val_b2[0]);
    }

    int l  = threadIdx.x & 63, w = threadIdx.x >> 6;
    int cl = l & 15, kq = l >> 4;       // MFMA col / k-quarter
    int mi = l >> 2, sl = l & 3;        // gather: move-in-tile / 16-ch slot
    ushort_t* Fl = Ft + w * 1664;

    // preload W1 B-fragments: bfr[ks][nt][e] = W1bf[ks*32+kq*8+e][nt*16+cl]
    short8 bfr[3][8];
    #pragma unroll
    for (int ks = 0; ks < 3; ks++) {
        #pragma unroll
        for (int nt = 0; nt < 8; nt++) {
            short8 s;
            #pragma unroll
            for (int e = 0; e < 8; e++)
                s[e] = (short)W1bfu[(ks * 32 + kq * 8 + e) * 128 + nt * 16 + cl];
            bfr[ks][nt] = s;
        }
    }
    float b1v[8], w2v[8];
    #pragma unroll
    for (int nt = 0; nt < 8; nt++) { b1v[nt] = b1[nt * 16 + cl]; w2v[nt] = w2[nt * 16 + cl]; }
    const float b2 = b2p[0];
    const uint4* fb4 = (const uint4*)fbf;   // [400][8] uint4 rows

    int gw = blockIdx.x * 4 + w;            // 0..4095
    for (int m0 = gw * 16; m0 < 400000; m0 += 4096 * 16) {
        int m = m0 + mi;
        int   pid = piece_id[m];
        int   nc  = num_cells[m];
        float2 an = ((const float2*)anchor)[m];
        float  sz = size_f[m];

        // gather-mean from L2-resident fmap: lane sums channels [sl*16, sl*16+16)
        float gacc[16];
        #pragma unroll
        for (int c = 0; c < 16; c++) gacc[c] = 0.f;
        for (int j = 0; j < nc; j++) {
            int2 cc = ((const int2*)cells)[m * 5 + j];
            int pc = cc.y * 20 + cc.x;
            uint4 qa = fb4[pc * 8 + sl * 2];
            uint4 qb = fb4[pc * 8 + sl * 2 + 1];
            gacc[0] += bflo(qa.x); gacc[1] += bfhi(qa.x);
            gacc[2] += bflo(qa.y); gacc[3] += bfhi(qa.y);
            gacc[4] += bflo(qa.z); gacc[5] += bfhi(qa.z);
            gacc[6] += bflo(qa.w); gacc[7] += bfhi(qa.w);
            gacc[8]  += bflo(qb.x); gacc[9]  += bfhi(qb.x);
            gacc[10] += bflo(qb.y); gacc[11] += bfhi(qb.y);
            gacc[12] += bflo(qb.z); gacc[13] += bfhi(qb.z);
            gacc[14] += bflo(qb.w); gacc[15] += bfhi(qb.w);
        }
        float scl = 1.0f / (float)nc;
        unsigned int pk[8];
        #pragma unroll
        for (int k = 0; k < 8; k++) {
            __hip_bfloat162 h2 = __float22bfloat162_rn(
                make_float2(gacc[2 * k] * scl, gacc[2 * k + 1] * scl));
            unsigned int u; __builtin_memcpy(&u, &h2, 4);
            pk[k] = u;
        }
        *(uint4*)(Fl + mi * 104 + sl * 16)     = make_uint4(pk[0], pk[1], pk[2], pk[3]);
        *(uint4*)(Fl + mi * 104 + sl * 16 + 8) = make_uint4(pk[4], pk[5], pk[6], pk[7]);
        if (sl == 0) { // piece embedding -> cols 64..79
            const uint4* pt = (const uint4*)ptbfu;
            *(uint4*)(Fl + mi * 104 + 64) = pt[pid * 2];
            *(uint4*)(Fl + mi * 104 + 72) = pt[pid * 2 + 1];
        }
        if (sl == 1) { // anchor, size, zero-pad -> cols 80..95
            unsigned int u0 = (unsigned int)f2bfu(an.x) | ((unsigned int)f2bfu(an.y) << 16);
            unsigned int u1 = (unsigned int)f2bfu(sz);
            *(uint4*)(Fl + mi * 104 + 80) = make_uint4(u0, u1, 0u, 0u);
            *(uint4*)(Fl + mi * 104 + 88) = make_uint4(0u, 0u, 0u, 0u);
        }
        // wave-local fence: cross-lane F writes must land before A-frag reads
        asm volatile("s_waitcnt lgkmcnt(0)" ::: "memory");

        short8 af0 = *(const short8*)(Fl + cl * 104 +      kq * 8);
        short8 af1 = *(const short8*)(Fl + cl * 104 + 32 + kq * 8);
        short8 af2 = *(const short8*)(Fl + cl * 104 + 64 + kq * 8);

        f32x4 acc[8];
        #pragma unroll
        for (int nt = 0; nt < 8; nt++) acc[nt] = (f32x4)0.f;
        #pragma unroll
        for (int nt = 0; nt < 8; nt++) {
            acc[nt] = __builtin_amdgcn_mfma_f32_16x16x32_bf16(af0, bfr[0][nt], acc[nt], 0, 0, 0);
            acc[nt] = __builtin_amdgcn_mfma_f32_16x16x32_bf16(af1, bfr[1][nt], acc[nt], 0, 0, 0);
            acc[nt] = __builtin_amdgcn_mfma_f32_16x16x32_bf16(af2, bfr[2][nt], acc[nt], 0, 0, 0);
        }

        // epilogue: relu(h)*w2, reduce over 16 col-lanes, write 16 logits
        float p0 = 0.f, p1 = 0.f, p2 = 0.f, p3 = 0.f;
        #pragma unroll
        for (int nt = 0; nt < 8; nt++) {
            p0 += fmaxf(acc[nt].x + b1v[nt], 0.f) * w2v[nt];
            p1 += fmaxf(acc[nt].y + b1v[nt], 0.f) * w2v[nt];
            p2 += fmaxf(acc[nt].z + b1v[nt], 0.f) * w2v[nt];
            p3 += fmaxf(acc[nt].w + b1v[nt], 0.f) * w2v[nt];
        }
        #pragma unroll
        for (int off = 1; off < 16; off <<= 1) {
            p0 += __shfl_xor(p0, off); p1 += __shfl_xor(p1, off);
            p2 += __shfl_xor(p2, off); p3 += __shfl_xor(p3, off);
        }
        if (cl < 4) {
            float v = p0;
            if (cl == 1) v = p1; else if (cl == 2) v = p2; else if (cl == 3) v = p3;
            out[m0 + kq * 4 + cl] = v + b2;
        }
    }
}

// ---------------------------------------------------------------------------
extern "C" void kernel_launch(void* const* d_in, const int* in_sizes, int n_in,
                              void* d_out, int out_size, void* d_ws, size_t ws_size,
                              hipStream_t stream) {
    const float* board      = (const float*)d_in[0];
    const float* self_rem   = (const float*)d_in[1];
    const float* opp_rem    = (const float*)d_in[2];
    const int*   piece_id   = (const int*)  d_in[3];
    const float* anchor     = (const float*)d_in[4];
    const int*   num_cells  = (const int*)  d_in[5];
    const float* size_f     = (const float*)d_in[6];
    const int*   cells      = (const int*)  d_in[7];
    const float* stem_w     = (const float*)d_in[8];
    const float* stem_b     = (const float*)d_in[9];
    const float* stem_s     = (const float*)d_in[10];
    const float* stem_o     = (const float*)d_in[11];
    const float* blk_w1     = (const float*)d_in[12];
    const float* blk_b1     = (const float*)d_in[13];
    const float* blk_s1     = (const float*)d_in[14];
    const float* blk_o1     = (const float*)d_in[15];
    const float* blk_w2     = (const float*)d_in[16];
    const float* blk_b2     = (const float*)d_in[17];
    const float* blk_s2     = (const float*)d_in[18];
    const float* blk_o2     = (const float*)d_in[19];
    const float* piece_tab  = (const float*)d_in[20];
    const float* mlp_w1     = (const float*)d_in[21];
    const float* mlp_b1     = (const float*)d_in[22];
    const float* mlp_w2     = (const float*)d_in[23];
    const float* mlp_b2     = (const float*)d_in[24];
    const float* val_conv_w = (const float*)d_in[25];
    const float* val_conv_b = (const float*)d_in[26];
    const float* val_w1     = (const float*)d_in[27];
    const float* val_b1     = (const float*)d_in[28];
    const float* val_w2     = (const float*)d_in[29];
    const float* val_b2     = (const float*)d_in[30];
    float* out = (float*)d_out;

    float* ws     = (float*)d_ws;
    float* xA     = ws;
    float* xB     = ws + 25600;
    float* wT     = ws + 51200;
    float* vwT    = ws + 346112;
    float* pooled = ws + 348160;
    ushort_t* fbf   = (ushort_t*)(ws + 348192);
    ushort_t* W1bfu = (ushort_t*)(ws + 360992);
    ushort_t* ptbfu = (ushort_t*)(ws + 367136);

    prep_kernel<<<180, 256, 0, stream>>>(
        board, stem_w, stem_b, stem_s, stem_o, xA,
        blk_w1, blk_w2, val_conv_w, piece_tab, mlp_w1,
        wT, vwT, W1bfu, ptbfu, pooled);

    for (int l = 0; l < 4; l++) {
        bool last = (l == 3);
        conv_ksplit<<<400, 512, 0, stream>>>(
            xA, xB, wT + (2 * l) * 36864,
            blk_b1 + l * 64, blk_s1 + l * 64, blk_o1 + l * 64,
            nullptr, nullptr, vwT, val_conv_b, pooled);
        conv_ksplit<<<400, 512, 0, stream>>>(
            xB, xA, wT + (2 * l + 1) * 36864,
            blk_b2 + l * 64, blk_s2 + l * 64, blk_o2 + l * 64,
            xA, last ? fbf : nullptr, vwT, val_conv_b, pooled);
    }

    policy_kernel<<<1024, 256, 0, stream>>>(
        fbf, piece_id, anchor, num_cells, size_f, cells,
        W1bfu, ptbfu, mlp_b1, mlp_w2, mlp_b2, out,
        pooled, self_rem, opp_rem, val_w1, val_b1, val_w2, val_b2);
}